// Round 15
// baseline (49.382 us; speedup 1.0000x reference)
//
#include <hip/hip_runtime.h>
#include <hip/hip_bf16.h>
#include <math.h>

#define CIN 256
#define COUT 768   // 3 * OUTC
#define OUTC 256
#define HH 64
#define WW 64
#define HW 4096

typedef unsigned int uint32;
typedef unsigned short ushort16;
typedef unsigned long long u64;

using short8 = __attribute__((ext_vector_type(8))) short;
using f32x4  = __attribute__((ext_vector_type(4))) float;
using hf2    = __attribute__((ext_vector_type(2))) _Float16;

__device__ inline uint32 pkbf2(float a, float b) {
    __hip_bfloat162 h = __float22bfloat162_rn(make_float2(a, b));
    union { __hip_bfloat162 h2; uint32 u; } cv; cv.h2 = h;
    return cv.u;
}
__device__ inline uint32 pkhf2(float a, float b) {
    union { _Float16 h[2]; uint32 u; } cv;
    cv.h[0] = (_Float16)a; cv.h[1] = (_Float16)b;
    return cv.u;
}
__device__ inline float dpp_xor1(float x) {
#if __has_builtin(__builtin_amdgcn_update_dpp)
    int i = __builtin_amdgcn_update_dpp(0, __float_as_int(x),
                                        0xB1, 0xF, 0xF, true);   // quad_perm [1,0,3,2]
    return __int_as_float(i);
#else
    return __shfl_xor(x, 1, 64);
#endif
}
__device__ inline float dpp_xor2(float x) {
#if __has_builtin(__builtin_amdgcn_update_dpp)
    int i = __builtin_amdgcn_update_dpp(0, __float_as_int(x),
                                        0x4E, 0xF, 0xF, true);   // quad_perm [2,3,0,1]
    return __int_as_float(i);
#else
    return __shfl_xor(x, 2, 64);
#endif
}
// f32 += dot(h2, h2) — v_dot2_f32_f16 if available, else unpack-fma
__device__ inline float dot2acc(hf2 a, hf2 b, float c) {
#if __has_builtin(__builtin_amdgcn_fdot2)
    return __builtin_amdgcn_fdot2(a, b, c, false);
#else
    c = fmaf((float)a[0], (float)b[0], c);
    return fmaf((float)a[1], (float)b[1], c);
#endif
}

// ---------------------------------------------------------------------------
// Kernel 1 (v7): QKV projection (EXACT R14 body, ~21.9 us).
// Output: qkv_f16[n][slot=d>>5][p][dlow=d&31]
// ---------------------------------------------------------------------------
#define LDSTR 40   // shorts per LDS row (32 + 8 pad)

__global__ __launch_bounds__(256) void qkv_gemm_kernel(
    const float* __restrict__ x, const float* __restrict__ wq,
    const float* __restrict__ bq, ushort16* __restrict__ qkv)
{
    __shared__ __align__(16) char smem[32768];
    ushort16* As = (ushort16*)smem;            // [128][LDSTR]
    ushort16* Bs = (ushort16*)smem + 128 * LDSTR;

    const int n   = blockIdx.z;
    const int d0  = blockIdx.y * 128;
    const int p0  = blockIdx.x * 128;
    const int tid = threadIdx.x;
    const int lane = tid & 63;
    const int wid  = tid >> 6;
    const int wm = wid >> 1;
    const int wn = wid & 1;

    const float* xb = x + (size_t)n * CIN * HW;

    const int arow = tid >> 2;
    const int akk  = (tid & 3) * 8;
    const float* aptr = wq + (size_t)(d0 + arow) * CIN + akk;
    const int bkg = (tid >> 6) * 8;
    const int bpg = (tid & 63) * 2;
    const float* bptr = xb + (size_t)bkg * HW + p0 + bpg;

    ushort16* awr0 = &As[arow * LDSTR + akk];
    ushort16* awr1 = &As[(arow + 64) * LDSTR + akk];
    ushort16* bwr0 = &Bs[bpg * LDSTR + bkg];
    ushort16* bwr1 = &Bs[(bpg + 1) * LDSTR + bkg];

    f32x4 acc[4][4];
    #pragma unroll
    for (int i = 0; i < 4; ++i)
        #pragma unroll
        for (int j = 0; j < 4; ++j) acc[i][j] = (f32x4){0.f, 0.f, 0.f, 0.f};

    const int lrow = lane & 15;
    const int lk   = (lane >> 4) * 8;

    float4 a0[4], a1[4];
    float2 b0[8], b1[8];

#define LOAD_SET(aS, bS, ko) do {                                         \
        aS[0] = *(const float4*)(aptr + (ko));                            \
        aS[1] = *(const float4*)(aptr + (ko) + 4);                        \
        aS[2] = *(const float4*)(aptr + (size_t)64 * CIN + (ko));         \
        aS[3] = *(const float4*)(aptr + (size_t)64 * CIN + (ko) + 4);     \
        _Pragma("unroll")                                                 \
        for (int j = 0; j < 8; ++j)                                       \
            bS[j] = *(const float2*)(bptr + (size_t)((ko) + j) * HW);     \
    } while (0)

#define WRITE_SET(aS, bS) do {                                            \
        uint32 w0 = pkbf2(aS[0].x, aS[0].y), w1 = pkbf2(aS[0].z, aS[0].w);\
        uint32 w2 = pkbf2(aS[1].x, aS[1].y), w3 = pkbf2(aS[1].z, aS[1].w);\
        *(uint4*)awr0 = make_uint4(w0, w1, w2, w3);                       \
        w0 = pkbf2(aS[2].x, aS[2].y); w1 = pkbf2(aS[2].z, aS[2].w);       \
        w2 = pkbf2(aS[3].x, aS[3].y); w3 = pkbf2(aS[3].z, aS[3].w);       \
        *(uint4*)awr1 = make_uint4(w0, w1, w2, w3);                       \
        uint4 c0, c1;                                                     \
        c0.x = pkbf2(bS[0].x, bS[1].x); c0.y = pkbf2(bS[2].x, bS[3].x);   \
        c0.z = pkbf2(bS[4].x, bS[5].x); c0.w = pkbf2(bS[6].x, bS[7].x);   \
        c1.x = pkbf2(bS[0].y, bS[1].y); c1.y = pkbf2(bS[2].y, bS[3].y);   \
        c1.z = pkbf2(bS[4].y, bS[5].y); c1.w = pkbf2(bS[6].y, bS[7].y);   \
        *(uint4*)bwr0 = c0;                                               \
        *(uint4*)bwr1 = c1;                                               \
    } while (0)

#define COMPUTE() do {                                                    \
        short8 af[4], bf[4];                                              \
        _Pragma("unroll")                                                 \
        for (int fm = 0; fm < 4; ++fm)                                    \
            af[fm] = *(const short8*)&As[(wm * 64 + fm * 16 + lrow) * LDSTR + lk]; \
        _Pragma("unroll")                                                 \
        for (int fn = 0; fn < 4; ++fn)                                    \
            bf[fn] = *(const short8*)&Bs[(wn * 64 + fn * 16 + lrow) * LDSTR + lk]; \
        _Pragma("unroll")                                                 \
        for (int fm = 0; fm < 4; ++fm)                                    \
            _Pragma("unroll")                                             \
            for (int fn = 0; fn < 4; ++fn)                                \
                acc[fm][fn] = __builtin_amdgcn_mfma_f32_16x16x32_bf16(    \
                    af[fm], bf[fn], acc[fm][fn], 0, 0, 0);                \
    } while (0)

    LOAD_SET(a0, b0, 0);
    LOAD_SET(a1, b1, 32);

    #pragma unroll 1
    for (int kt = 0; kt < 8; kt += 2) {
        __syncthreads();
        WRITE_SET(a0, b0);
        if (kt + 2 < 8) LOAD_SET(a0, b0, (kt + 2) * 32);
        __syncthreads();
        COMPUTE();

        __syncthreads();
        WRITE_SET(a1, b1);
        if (kt + 3 < 8) LOAD_SET(a1, b1, (kt + 3) * 32);
        __syncthreads();
        COMPUTE();
    }
#undef LOAD_SET
#undef WRITE_SET
#undef COMPUTE

    __syncthreads();

    u64* E = (u64*)smem + (size_t)wid * 1024;

    const int hi4 = lane >> 4;
    #pragma unroll
    for (int fm = 0; fm < 4; ++fm) {
        const int D = d0 + wm * 64 + fm * 16 + hi4 * 4;
        const float4 bias = *(const float4*)(&bq[D]);
        const int cell = fm * 2 + (hi4 >> 1);
        const int half = hi4 & 1;
        #pragma unroll
        for (int fn = 0; fn < 4; ++fn) {
            const int pl = fn * 16 + lrow;
            f32x4 v = acc[fm][fn];
            u64 pk = (u64)pkhf2(v[0] + bias.x, v[1] + bias.y)
                   | ((u64)pkhf2(v[2] + bias.z, v[3] + bias.w) << 32);
            E[pl * 16 + (cell ^ (pl & 7)) * 2 + half] = pk;
        }
    }
    const int pl4 = lane >> 2;
    const int dq  = lane & 3;
    ushort16* qn = qkv + (size_t)n * COUT * HW;
    #pragma unroll
    for (int s = 0; s < 2; ++s) {
        const int D = d0 + wm * 64 + s * 32;
        const int slot = D >> 5;
        ushort16* sb2 = qn + (size_t)slot * (HW * 32);
        #pragma unroll
        for (int g = 0; g < 4; ++g) {
            const int prow = g * 16 + pl4;
            const int c = s * 4 + dq;
            const uint4 val = *(const uint4*)&E[prow * 16 + ((c ^ (prow & 7)) * 2)];
            *(uint4*)(sb2 + (size_t)(p0 + wn * 64 + prow) * 32 + dq * 8) = val;
        }
    }
}

// ---------------------------------------------------------------------------
// Kernel 2 (v8): 5x5 neighborhood attention.
// Tile 4x16 px, 4 threads/px (8 dims each): 2048 blocks = 8 blocks/CU,
// 32 waves/CU (2x TLP vs v5). SINGLE 10-KB LDS buffer time-shared K->V
// (T14: V global loads issued before score phase, written after).
// QK: 4 fdot2 + quad butterfly. PV: 4 pk_fma. setprio around compute.
// ---------------------------------------------------------------------------
#define TR 4
#define TC 16
#define HR 8          // TR + 4
#define HC 20         // TC + 4
#define NPIX (HR*HC)  // 160
#define NCELL (NPIX*4) // 640 uint4 = 10.2 KB

__global__ __launch_bounds__(256) void attn_kernel(
    const ushort16* __restrict__ qkv, float* __restrict__ out)
{
    __shared__ uint4 KVs[NCELL];   // 10.2 KB, K then V (time-shared)

    const int n    = blockIdx.z;
    const int head = blockIdx.y;
    const int ht = blockIdx.x >> 2;       // 0..15
    const int wt = blockIdx.x & 3;        // 0..3
    const int h0 = ht * TR;
    const int w0 = wt * TC;

    const int tid  = threadIdx.x;
    const int quar = tid & 3;             // d-quarter: dims 8q..8q+7
    const int pid  = tid >> 2;            // 0..63
    const int tr = pid >> 4, wc = pid & 15;
    const int h = h0 + tr, w = w0 + wc;
    const int p = h * WW + w;

    const uint4* Qb = (const uint4*)(qkv + ((size_t)(n * 24 + head)) * HW * 32);
    const uint4* Kb = (const uint4*)(qkv + ((size_t)(n * 24 + 8 + head)) * HW * 32);
    const uint4* Vb = (const uint4*)(qkv + ((size_t)(n * 24 + 16 + head)) * HW * 32);

    // ---- stage K into LDS; issue V loads to regs (write later) ----
    #pragma unroll
    for (int it = 0; it < 3; ++it) {
        const int c = tid + it * 256;
        if (c < NCELL) {
            const int pix = c >> 2, i = c & 3;
            const int hr = pix / HC, cw = pix - hr * HC;
            const int hh = h0 + hr - 2, ww = w0 + cw - 2;
            if (hh >= 0 && hh < HH && ww >= 0 && ww < WW) {
                const int pp = hh * WW + ww;
                KVs[(pix * 4 + i) ^ (pix & 7)] = Kb[(size_t)pp * 4 + i];
            }
        }
    }
    uint4 vreg[3];
    #pragma unroll
    for (int it = 0; it < 3; ++it) {
        const int c = tid + it * 256;
        if (c < NCELL) {
            const int pix = c >> 2, i = c & 3;
            const int hr = pix / HC, cw = pix - hr * HC;
            const int hh = h0 + hr - 2, ww = w0 + cw - 2;
            if (hh >= 0 && hh < HH && ww >= 0 && ww < WW)
                vreg[it] = Vb[(size_t)(hh * WW + ww) * 4 + i];
        }
    }

    // Q: this thread's 8 dims, packed as 4x half2
    hf2 q[4];
    {
        union { uint4 u; hf2 h[4]; } c;
        c.u = Qb[(size_t)p * 4 + quar];
        #pragma unroll
        for (int i = 0; i < 4; ++i) q[i] = c.h[i];
    }

    __syncthreads();   // K staged

    // ---- scores ----
    __builtin_amdgcn_s_setprio(1);
    float sc[25];
    #pragma unroll
    for (int ky = 0; ky < 5; ++ky) {
        const int hh = h + ky - 2;
        const int hr = tr + ky;
        #pragma unroll
        for (int kx = 0; kx < 5; ++kx) {
            const int ww = w + kx - 2;
            const bool valid = (hh >= 0 && hh < HH && ww >= 0 && ww < WW);
            float t = 0.f;
            if (valid) {
                const int pix = hr * HC + (wc + kx);
                union { uint4 u; hf2 hh2[4]; } a;
                a.u = KVs[(pix * 4 + quar) ^ (pix & 7)];
                t = dot2acc(q[0], a.hh2[0], t);
                t = dot2acc(q[1], a.hh2[1], t);
                t = dot2acc(q[2], a.hh2[2], t);
                t = dot2acc(q[3], a.hh2[3], t);
            }
            t += dpp_xor1(t);
            t += dpp_xor2(t);
            sc[ky * 5 + kx] = valid ? t : -1e30f;
        }
    }
    __builtin_amdgcn_s_setprio(0);

    __syncthreads();   // all K reads done; LDS reusable

    // ---- write V into the same buffer ----
    #pragma unroll
    for (int it = 0; it < 3; ++it) {
        const int c = tid + it * 256;
        if (c < NCELL) {
            const int pix = c >> 2, i = c & 3;
            const int hr = pix / HC, cw = pix - hr * HC;
            const int hh = h0 + hr - 2, ww = w0 + cw - 2;
            if (hh >= 0 && hh < HH && ww >= 0 && ww < WW)
                KVs[(pix * 4 + i) ^ (pix & 7)] = vreg[it];
        }
    }

    // softmax (register-only; overlaps other waves' V writes)
    float m = sc[0];
    #pragma unroll
    for (int k = 1; k < 25; ++k) m = fmaxf(m, sc[k]);
    float sum = 0.f;
    #pragma unroll
    for (int k = 0; k < 25; ++k) {
        float e = __expf(sc[k] - m);
        sc[k] = e;
        sum += e;
    }
    const float inv = 1.f / sum;

    __syncthreads();   // V staged

    // ---- PV ----
    __builtin_amdgcn_s_setprio(1);
    hf2 acch[4];
    #pragma unroll
    for (int i = 0; i < 4; ++i) acch[i] = (hf2){(_Float16)0.f, (_Float16)0.f};
    #pragma unroll
    for (int ky = 0; ky < 5; ++ky) {
        const int hh = h + ky - 2;
        if (hh < 0 || hh >= HH) continue;
        const int hr = tr + ky;
        #pragma unroll
        for (int kx = 0; kx < 5; ++kx) {
            const int ww = w + kx - 2;
            if (ww < 0 || ww >= WW) continue;
            const _Float16 af = (_Float16)sc[ky * 5 + kx];
            const hf2 ah = (hf2){af, af};
            const int pix = hr * HC + (wc + kx);
            union { uint4 u; hf2 hh2[4]; } v;
            v.u = KVs[(pix * 4 + quar) ^ (pix & 7)];
            acch[0] += ah * v.hh2[0];
            acch[1] += ah * v.hh2[1];
            acch[2] += ah * v.hh2[2];
            acch[3] += ah * v.hh2[3];
        }
    }
    __builtin_amdgcn_s_setprio(0);

    // ---- store: dims quar*8 .. quar*8+7 ----
    float* Ob = out + ((size_t)(n * 8 + head) * 32 + quar * 8) * HW + p;
    #pragma unroll
    for (int i = 0; i < 4; ++i) {
        Ob[(size_t)(2*i)   * HW] = (float)acch[i][0] * inv;
        Ob[(size_t)(2*i+1) * HW] = (float)acch[i][1] * inv;
    }
}

// ---------------------------------------------------------------------------
extern "C" void kernel_launch(void* const* d_in, const int* in_sizes, int n_in,
                              void* d_out, int out_size, void* d_ws, size_t ws_size,
                              hipStream_t stream) {
    const float* x  = (const float*)d_in[0];   // (4, 256, 64, 64)
    const float* wq = (const float*)d_in[1];   // (768, 256)
    const float* bq = (const float*)d_in[2];   // (768,)
    float* out = (float*)d_out;                // (4, 256, 64, 64) fp32
    ushort16* qkv = (ushort16*)d_ws;           // fp16 [4][24][4096][32] = 25 MB

    dim3 g1(HW / 128, COUT / 128, 4);          // (32, 6, 4) = 768 blocks
    qkv_gemm_kernel<<<g1, 256, 0, stream>>>(x, wq, bq, qkv);

    dim3 g2(64, 8, 4);                         // (16 ht x 4 wt, 8 heads, 4 n) = 2048
    attn_kernel<<<g2, 256, 0, stream>>>(qkv, out);
}

// Round 16
// 41.828 us; speedup vs baseline: 1.1806x; 1.1806x over previous
//
#include <hip/hip_runtime.h>
#include <hip/hip_bf16.h>
#include <math.h>

#define CIN 256
#define COUT 768   // 3 * OUTC
#define OUTC 256
#define HH 64
#define WW 64
#define HW 4096

typedef unsigned int uint32;
typedef unsigned short ushort16;
typedef unsigned long long u64;

using short8 = __attribute__((ext_vector_type(8))) short;
using f32x4  = __attribute__((ext_vector_type(4))) float;
using hf2    = __attribute__((ext_vector_type(2))) _Float16;

__device__ inline uint32 pkbf2(float a, float b) {
    __hip_bfloat162 h = __float22bfloat162_rn(make_float2(a, b));
    union { __hip_bfloat162 h2; uint32 u; } cv; cv.h2 = h;
    return cv.u;
}
__device__ inline uint32 pkhf2(float a, float b) {
    union { _Float16 h[2]; uint32 u; } cv;
    cv.h[0] = (_Float16)a; cv.h[1] = (_Float16)b;
    return cv.u;
}
__device__ inline float dpp_xor1(float x) {
#if __has_builtin(__builtin_amdgcn_update_dpp)
    int i = __builtin_amdgcn_update_dpp(0, __float_as_int(x),
                                        0xB1, 0xF, 0xF, true);   // quad_perm [1,0,3,2]
    return __int_as_float(i);
#else
    return __shfl_xor(x, 1, 64);
#endif
}
// f32 += dot(h2, h2) — v_dot2_f32_f16 if available, else unpack-fma
__device__ inline float dot2acc(hf2 a, hf2 b, float c) {
#if __has_builtin(__builtin_amdgcn_fdot2)
    return __builtin_amdgcn_fdot2(a, b, c, false);
#else
    c = fmaf((float)a[0], (float)b[0], c);
    return fmaf((float)a[1], (float)b[1], c);
#endif
}

// ---------------------------------------------------------------------------
// Kernel 1 (v7): QKV projection (EXACT R14 body, ~21.9 us).
// Output: qkv_f16[n][slot=d>>5][p][dlow=d&31]
// ---------------------------------------------------------------------------
#define LDSTR 40   // shorts per LDS row (32 + 8 pad)

__global__ __launch_bounds__(256) void qkv_gemm_kernel(
    const float* __restrict__ x, const float* __restrict__ wq,
    const float* __restrict__ bq, ushort16* __restrict__ qkv)
{
    __shared__ __align__(16) char smem[32768];
    ushort16* As = (ushort16*)smem;            // [128][LDSTR]
    ushort16* Bs = (ushort16*)smem + 128 * LDSTR;

    const int n   = blockIdx.z;
    const int d0  = blockIdx.y * 128;
    const int p0  = blockIdx.x * 128;
    const int tid = threadIdx.x;
    const int lane = tid & 63;
    const int wid  = tid >> 6;
    const int wm = wid >> 1;
    const int wn = wid & 1;

    const float* xb = x + (size_t)n * CIN * HW;

    const int arow = tid >> 2;
    const int akk  = (tid & 3) * 8;
    const float* aptr = wq + (size_t)(d0 + arow) * CIN + akk;
    const int bkg = (tid >> 6) * 8;
    const int bpg = (tid & 63) * 2;
    const float* bptr = xb + (size_t)bkg * HW + p0 + bpg;

    ushort16* awr0 = &As[arow * LDSTR + akk];
    ushort16* awr1 = &As[(arow + 64) * LDSTR + akk];
    ushort16* bwr0 = &Bs[bpg * LDSTR + bkg];
    ushort16* bwr1 = &Bs[(bpg + 1) * LDSTR + bkg];

    f32x4 acc[4][4];
    #pragma unroll
    for (int i = 0; i < 4; ++i)
        #pragma unroll
        for (int j = 0; j < 4; ++j) acc[i][j] = (f32x4){0.f, 0.f, 0.f, 0.f};

    const int lrow = lane & 15;
    const int lk   = (lane >> 4) * 8;

    float4 a0[4], a1[4];
    float2 b0[8], b1[8];

#define LOAD_SET(aS, bS, ko) do {                                         \
        aS[0] = *(const float4*)(aptr + (ko));                            \
        aS[1] = *(const float4*)(aptr + (ko) + 4);                        \
        aS[2] = *(const float4*)(aptr + (size_t)64 * CIN + (ko));         \
        aS[3] = *(const float4*)(aptr + (size_t)64 * CIN + (ko) + 4);     \
        _Pragma("unroll")                                                 \
        for (int j = 0; j < 8; ++j)                                       \
            bS[j] = *(const float2*)(bptr + (size_t)((ko) + j) * HW);     \
    } while (0)

#define WRITE_SET(aS, bS) do {                                            \
        uint32 w0 = pkbf2(aS[0].x, aS[0].y), w1 = pkbf2(aS[0].z, aS[0].w);\
        uint32 w2 = pkbf2(aS[1].x, aS[1].y), w3 = pkbf2(aS[1].z, aS[1].w);\
        *(uint4*)awr0 = make_uint4(w0, w1, w2, w3);                       \
        w0 = pkbf2(aS[2].x, aS[2].y); w1 = pkbf2(aS[2].z, aS[2].w);       \
        w2 = pkbf2(aS[3].x, aS[3].y); w3 = pkbf2(aS[3].z, aS[3].w);       \
        *(uint4*)awr1 = make_uint4(w0, w1, w2, w3);                       \
        uint4 c0, c1;                                                     \
        c0.x = pkbf2(bS[0].x, bS[1].x); c0.y = pkbf2(bS[2].x, bS[3].x);   \
        c0.z = pkbf2(bS[4].x, bS[5].x); c0.w = pkbf2(bS[6].x, bS[7].x);   \
        c1.x = pkbf2(bS[0].y, bS[1].y); c1.y = pkbf2(bS[2].y, bS[3].y);   \
        c1.z = pkbf2(bS[4].y, bS[5].y); c1.w = pkbf2(bS[6].y, bS[7].y);   \
        *(uint4*)bwr0 = c0;                                               \
        *(uint4*)bwr1 = c1;                                               \
    } while (0)

#define COMPUTE() do {                                                    \
        short8 af[4], bf[4];                                              \
        _Pragma("unroll")                                                 \
        for (int fm = 0; fm < 4; ++fm)                                    \
            af[fm] = *(const short8*)&As[(wm * 64 + fm * 16 + lrow) * LDSTR + lk]; \
        _Pragma("unroll")                                                 \
        for (int fn = 0; fn < 4; ++fn)                                    \
            bf[fn] = *(const short8*)&Bs[(wn * 64 + fn * 16 + lrow) * LDSTR + lk]; \
        _Pragma("unroll")                                                 \
        for (int fm = 0; fm < 4; ++fm)                                    \
            _Pragma("unroll")                                             \
            for (int fn = 0; fn < 4; ++fn)                                \
                acc[fm][fn] = __builtin_amdgcn_mfma_f32_16x16x32_bf16(    \
                    af[fm], bf[fn], acc[fm][fn], 0, 0, 0);                \
    } while (0)

    LOAD_SET(a0, b0, 0);
    LOAD_SET(a1, b1, 32);

    #pragma unroll 1
    for (int kt = 0; kt < 8; kt += 2) {
        __syncthreads();
        WRITE_SET(a0, b0);
        if (kt + 2 < 8) LOAD_SET(a0, b0, (kt + 2) * 32);
        __syncthreads();
        COMPUTE();

        __syncthreads();
        WRITE_SET(a1, b1);
        if (kt + 3 < 8) LOAD_SET(a1, b1, (kt + 3) * 32);
        __syncthreads();
        COMPUTE();
    }
#undef LOAD_SET
#undef WRITE_SET
#undef COMPUTE

    __syncthreads();

    u64* E = (u64*)smem + (size_t)wid * 1024;

    const int hi4 = lane >> 4;
    #pragma unroll
    for (int fm = 0; fm < 4; ++fm) {
        const int D = d0 + wm * 64 + fm * 16 + hi4 * 4;
        const float4 bias = *(const float4*)(&bq[D]);
        const int cell = fm * 2 + (hi4 >> 1);
        const int half = hi4 & 1;
        #pragma unroll
        for (int fn = 0; fn < 4; ++fn) {
            const int pl = fn * 16 + lrow;
            f32x4 v = acc[fm][fn];
            u64 pk = (u64)pkhf2(v[0] + bias.x, v[1] + bias.y)
                   | ((u64)pkhf2(v[2] + bias.z, v[3] + bias.w) << 32);
            E[pl * 16 + (cell ^ (pl & 7)) * 2 + half] = pk;
        }
    }
    const int pl4 = lane >> 2;
    const int dq  = lane & 3;
    ushort16* qn = qkv + (size_t)n * COUT * HW;
    #pragma unroll
    for (int s = 0; s < 2; ++s) {
        const int D = d0 + wm * 64 + s * 32;
        const int slot = D >> 5;
        ushort16* sb2 = qn + (size_t)slot * (HW * 32);
        #pragma unroll
        for (int g = 0; g < 4; ++g) {
            const int prow = g * 16 + pl4;
            const int c = s * 4 + dq;
            const uint4 val = *(const uint4*)&E[prow * 16 + ((c ^ (prow & 7)) * 2)];
            *(uint4*)(sb2 + (size_t)(p0 + wn * 64 + prow) * 32 + dq * 8) = val;
        }
    }
}

// ---------------------------------------------------------------------------
// Kernel 2 (v9): 5x5 neighborhood attention, 2 q-px/thread sliding window.
// Thread = (q-pair, d-half). Per dy-row: read the 6-cell union window ONCE
// (12 unit-reads), reuse for 2 q x 5 kx -> 120 unit-reads/px (was 200).
// Tile 4 rows x 64 cols (full width); halo 8x68; K+V zero-filled OOB.
// Swizzle ^((pix>>1)&7): bijective, spreads the stride-2-pixel read pattern
// across all bank groups (b128 floor).
// ---------------------------------------------------------------------------
#define TR 4
#define HC 68          // 64 + 4
#define HR 8           // TR + 4
#define NPIX (HR*HC)   // 544
#define NCELL (NPIX*4) // 2176 units -> 34.8 KB per buffer

__global__ __launch_bounds__(256) void attn_kernel(
    const ushort16* __restrict__ qkv, float* __restrict__ out)
{
    __shared__ uint4 Ks[NCELL];   // 34.8 KB
    __shared__ uint4 Vs[NCELL];   // 34.8 KB

    const int n    = blockIdx.z;
    const int head = blockIdx.y;
    const int h0   = blockIdx.x * TR;

    const int tid  = threadIdx.x;
    const int half = tid & 1;            // d-half: dims half*16 .. +15
    const int g    = (tid >> 1) & 31;    // q-pair: cols 2g, 2g+1
    const int tr   = tid >> 6;           // row in tile

    const int h  = h0 + tr;
    const int w0q = 2 * g;               // local col of q0

    const uint4* Qb = (const uint4*)(qkv + ((size_t)(n * 24 + head)) * HW * 32);
    const uint4* Kb = (const uint4*)(qkv + ((size_t)(n * 24 + 8 + head)) * HW * 32);
    const uint4* Vb = (const uint4*)(qkv + ((size_t)(n * 24 + 16 + head)) * HW * 32);

    // ---- stage K and V halo (zero-fill OOB) ----
    const uint4 zero4 = make_uint4(0u, 0u, 0u, 0u);
    for (int c = tid; c < 2 * NCELL; c += 256) {
        const int b  = (c >= NCELL);
        const int cc = c - b * NCELL;
        const int pix = cc >> 2, u = cc & 3;
        const int hr = pix / HC, cw = pix - hr * HC;
        const int hh = h0 + hr - 2, ww = cw - 2;
        const int unit = (pix * 4 + u) ^ ((pix >> 1) & 7);
        uint4 v = zero4;
        if (hh >= 0 && hh < HH && ww >= 0 && ww < WW)
            v = (b ? Vb : Kb)[(size_t)(hh * WW + ww) * 4 + u];
        (b ? Vs : Ks)[unit] = v;
    }

    // Q: both q's, this thread's 16 dims (2 units each), packed hf2
    hf2 q0[8], q1[8];
    {
        const size_t pbase = (size_t)(h * WW + w0q) * 4 + half * 2;
        union { uint4 u; hf2 h2[4]; } c;
        c.u = Qb[pbase + 0];
        #pragma unroll
        for (int i = 0; i < 4; ++i) q0[i] = c.h2[i];
        c.u = Qb[pbase + 1];
        #pragma unroll
        for (int i = 0; i < 4; ++i) q0[4 + i] = c.h2[i];
        c.u = Qb[pbase + 4];          // q1 = next pixel (+4 units)
        #pragma unroll
        for (int i = 0; i < 4; ++i) q1[i] = c.h2[i];
        c.u = Qb[pbase + 5];
        #pragma unroll
        for (int i = 0; i < 4; ++i) q1[4 + i] = c.h2[i];
    }

    __syncthreads();

    // ---- QK: per dy, read 6-cell window once, slide across kx ----
    float sc0[25], sc1[25];
    #pragma unroll
    for (int ky = 0; ky < 5; ++ky) {
        const int hr = tr + ky;
        union { uint4 u; hf2 h2[4]; } cell[12];
        #pragma unroll
        for (int c = 0; c < 6; ++c) {
            const int pix = hr * HC + w0q + c;
            const int swz = (pix >> 1) & 7;
            cell[c * 2 + 0].u = Ks[(pix * 4 + half * 2 + 0) ^ swz];
            cell[c * 2 + 1].u = Ks[(pix * 4 + half * 2 + 1) ^ swz];
        }
        #pragma unroll
        for (int kx = 0; kx < 5; ++kx) {
            float t0 = 0.f, t1 = 0.f;
            #pragma unroll
            for (int i = 0; i < 4; ++i) {
                t0 = dot2acc(q0[i],     cell[kx * 2 + 0].h2[i], t0);
                t0 = dot2acc(q0[4 + i], cell[kx * 2 + 1].h2[i], t0);
                t1 = dot2acc(q1[i],     cell[(kx + 1) * 2 + 0].h2[i], t1);
                t1 = dot2acc(q1[4 + i], cell[(kx + 1) * 2 + 1].h2[i], t1);
            }
            sc0[ky * 5 + kx] = t0;
            sc1[ky * 5 + kx] = t1;
        }
    }

    // combine halves (lane^1 = other d-half of same q-pair) + mask
    #pragma unroll
    for (int ky = 0; ky < 5; ++ky) {
        const int hh = h + ky - 2;
        const bool hok = (hh >= 0 && hh < HH);
        #pragma unroll
        for (int kx = 0; kx < 5; ++kx) {
            const int k = ky * 5 + kx;
            const int ww0 = w0q + kx - 2;
            float t0 = sc0[k] + dpp_xor1(sc0[k]);
            float t1 = sc1[k] + dpp_xor1(sc1[k]);
            sc0[k] = (hok && ww0 >= 0 && ww0 < WW) ? t0 : -1e30f;
            sc1[k] = (hok && ww0 + 1 >= 0 && ww0 + 1 < WW) ? t1 : -1e30f;
        }
    }

    // softmax per q
    float m0 = sc0[0], m1 = sc1[0];
    #pragma unroll
    for (int k = 1; k < 25; ++k) { m0 = fmaxf(m0, sc0[k]); m1 = fmaxf(m1, sc1[k]); }
    float sum0 = 0.f, sum1 = 0.f;
    #pragma unroll
    for (int k = 0; k < 25; ++k) {
        float e0 = __expf(sc0[k] - m0); sc0[k] = e0; sum0 += e0;
        float e1 = __expf(sc1[k] - m1); sc1[k] = e1; sum1 += e1;
    }
    const float inv0 = 1.f / sum0;
    const float inv1 = 1.f / sum1;

    // ---- PV: same sliding window over V (OOB cells are zero; a=0 there) ----
    hf2 acc0[4], acc1[4];
    #pragma unroll
    for (int i = 0; i < 4; ++i) {
        acc0[i] = (hf2){(_Float16)0.f, (_Float16)0.f};
        acc1[i] = (hf2){(_Float16)0.f, (_Float16)0.f};
    }
    #pragma unroll
    for (int ky = 0; ky < 5; ++ky) {
        const int hr = tr + ky;
        union { uint4 u; hf2 h2[4]; } cell[12];
        #pragma unroll
        for (int c = 0; c < 6; ++c) {
            const int pix = hr * HC + w0q + c;
            const int swz = (pix >> 1) & 7;
            cell[c * 2 + 0].u = Vs[(pix * 4 + half * 2 + 0) ^ swz];
            cell[c * 2 + 1].u = Vs[(pix * 4 + half * 2 + 1) ^ swz];
        }
        #pragma unroll
        for (int kx = 0; kx < 5; ++kx) {
            const int k = ky * 5 + kx;
            // masked scores are exp(-1e30-m) = 0 -> OOB contributes 0
            const _Float16 a0 = (_Float16)sc0[k];
            const _Float16 a1 = (_Float16)sc1[k];
            const hf2 ah0 = (hf2){a0, a0};
            const hf2 ah1 = (hf2){a1, a1};
            #pragma unroll
            for (int i = 0; i < 4; ++i) {
                acc0[i] += ah0 * cell[kx * 2 + (i >> 1)].h2[(i & 1) * 2 + 0];
                acc0[i] += ah0 * (hf2){(_Float16)0.f, (_Float16)0.f}; // keep shape
            }
            // unrolled explicit (clearer): redo properly below
        }
    }

    // NOTE: the loop above was mis-sketched; do PV properly:
    #pragma unroll
    for (int i = 0; i < 4; ++i) {
        acc0[i] = (hf2){(_Float16)0.f, (_Float16)0.f};
        acc1[i] = (hf2){(_Float16)0.f, (_Float16)0.f};
    }
    hf2 acc0b[4], acc1b[4];
    #pragma unroll
    for (int i = 0; i < 4; ++i) {
        acc0b[i] = (hf2){(_Float16)0.f, (_Float16)0.f};
        acc1b[i] = (hf2){(_Float16)0.f, (_Float16)0.f};
    }
    #pragma unroll
    for (int ky = 0; ky < 5; ++ky) {
        const int hr = tr + ky;
        union { uint4 u; hf2 h2[4]; } cell[12];
        #pragma unroll
        for (int c = 0; c < 6; ++c) {
            const int pix = hr * HC + w0q + c;
            const int swz = (pix >> 1) & 7;
            cell[c * 2 + 0].u = Vs[(pix * 4 + half * 2 + 0) ^ swz];
            cell[c * 2 + 1].u = Vs[(pix * 4 + half * 2 + 1) ^ swz];
        }
        #pragma unroll
        for (int kx = 0; kx < 5; ++kx) {
            const int k = ky * 5 + kx;
            const _Float16 a0 = (_Float16)sc0[k];
            const _Float16 a1 = (_Float16)sc1[k];
            const hf2 ah0 = (hf2){a0, a0};
            const hf2 ah1 = (hf2){a1, a1};
            #pragma unroll
            for (int i = 0; i < 4; ++i) {
                acc0[i]  += ah0 * cell[kx * 2 + 0].h2[i];        // dims lo-unit
                acc0b[i] += ah0 * cell[kx * 2 + 1].h2[i];        // dims hi-unit
                acc1[i]  += ah1 * cell[(kx + 1) * 2 + 0].h2[i];
                acc1b[i] += ah1 * cell[(kx + 1) * 2 + 1].h2[i];
            }
        }
    }

    // ---- store: dims half*16..+15, pixels (w0q, w0q+1) as float2 ----
    float* Ob = out + ((size_t)(n * 8 + head) * 32 + half * 16) * HW
                    + h * WW + w0q;
    #pragma unroll
    for (int i = 0; i < 4; ++i) {
        // unit-lo dims: half*16 + 2i, 2i+1
        *(float2*)&Ob[(size_t)(2 * i) * HW] =
            make_float2((float)acc0[i][0] * inv0, (float)acc1[i][0] * inv1);
        *(float2*)&Ob[(size_t)(2 * i + 1) * HW] =
            make_float2((float)acc0[i][1] * inv0, (float)acc1[i][1] * inv1);
        // unit-hi dims: half*16 + 8 + 2i, 2i+1
        *(float2*)&Ob[(size_t)(8 + 2 * i) * HW] =
            make_float2((float)acc0b[i][0] * inv0, (float)acc1b[i][0] * inv1);
        *(float2*)&Ob[(size_t)(8 + 2 * i + 1) * HW] =
            make_float2((float)acc0b[i][1] * inv0, (float)acc1b[i][1] * inv1);
    }
}

// ---------------------------------------------------------------------------
extern "C" void kernel_launch(void* const* d_in, const int* in_sizes, int n_in,
                              void* d_out, int out_size, void* d_ws, size_t ws_size,
                              hipStream_t stream) {
    const float* x  = (const float*)d_in[0];   // (4, 256, 64, 64)
    const float* wq = (const float*)d_in[1];   // (768, 256)
    const float* bq = (const float*)d_in[2];   // (768,)
    float* out = (float*)d_out;                // (4, 256, 64, 64) fp32
    ushort16* qkv = (ushort16*)d_ws;           // fp16 [4][24][4096][32] = 25 MB

    dim3 g1(HW / 128, COUT / 128, 4);          // (32, 6, 4) = 768 blocks
    qkv_gemm_kernel<<<g1, 256, 0, stream>>>(x, wq, bq, qkv);

    dim3 g2(16, 8, 4);                         // (16 h-tiles, 8 heads, 4 n) = 512
    attn_kernel<<<g2, 256, 0, stream>>>(qkv, out);
}